// Round 5
// baseline (797.905 us; speedup 1.0000x reference)
//
#include <hip/hip_runtime.h>

#define D 128
#define EPS 1e-10f
#define ATILE 16
#define THR 14.0f
#define AGRID 4096

// ---------------------------------------------------------------------------
// K1: row_ptr via binary search (node2graph sorted) + zero the 3 work-steal
// counters (runs before all attn passes every call — replay-safe)
// ---------------------------------------------------------------------------
__global__ void rowptr_kernel(const int* __restrict__ n2g, int N_, int B_,
                              int* __restrict__ row_ptr, int* __restrict__ ctrs) {
    if (blockIdx.x == 0 && threadIdx.x < 3) ctrs[threadIdx.x] = 0;
    int b = blockIdx.x * 256 + threadIdx.x;
    if (b > B_) return;
    if (b == B_) { row_ptr[b] = N_; return; }
    int lo = 0, hi = N_;
    while (lo < hi) {
        int mid = (lo + hi) >> 1;
        if (n2g[mid] < b) lo = mid + 1; else hi = mid;
    }
    row_ptr[b] = lo;
}

// ---------------------------------------------------------------------------
// K2: b_sum = b_ih + b_hh; step-1 constants h1, c1
// ---------------------------------------------------------------------------
__global__ void init_consts_kernel(const float* __restrict__ b_ih,
                                   const float* __restrict__ b_hh,
                                   float* __restrict__ b_sum,
                                   float* __restrict__ c1,
                                   float* __restrict__ h1) {
    int t = threadIdx.x;  // 512 threads, 1 block
    __shared__ float bs[512];
    float v = b_ih[t] + b_hh[t];
    b_sum[t] = v;
    bs[t] = v;
    __syncthreads();
    if (t < D) {
        float ig = 1.f / (1.f + __expf(-bs[t]));
        float gg = tanhf(bs[256 + t]);
        float c  = ig * gg;
        float og = 1.f / (1.f + __expf(-bs[384 + t]));
        c1[t] = c;
        h1[t] = og * tanhf(c);
    }
}

// ---------------------------------------------------------------------------
// K3: W1 = w_ih[:, :D] + w_hh; const2 = b_sum + W1 @ h1
// ---------------------------------------------------------------------------
__global__ void init_w1_kernel(const float* __restrict__ w_ih,
                               const float* __restrict__ w_hh,
                               const float* __restrict__ b_sum,
                               const float* __restrict__ h1,
                               float* __restrict__ W1,
                               float* __restrict__ const2) {
    int j = blockIdx.x, k = threadIdx.x;
    float w = w_ih[j * 256 + k] + w_hh[j * 128 + k];
    W1[j * 128 + k] = w;
    __shared__ float red[128];
    red[k] = w * h1[k];
    __syncthreads();
    for (int s = 64; s > 0; s >>= 1) {
        if (k < s) red[k] += red[k + s];
        __syncthreads();
    }
    if (k == 0) const2[j] = b_sum[j] + red[0];
}

// ---------------------------------------------------------------------------
// K4: tiled GEMM: gates[b][j] = base[j] + A1[b]·Wa[j] (+ A2[b]·Wb[j])
// ---------------------------------------------------------------------------
#define BM 64
#define BN 64
#define BK 32
__global__ __launch_bounds__(256) void lstm_gemm_kernel(
    const float* __restrict__ A1, const float* __restrict__ Wa, int wa_stride,
    const float* __restrict__ A2, const float* __restrict__ Wb, int wb_stride,
    const float* __restrict__ base, float* __restrict__ gates, int B_) {
    __shared__ float As[BM][BK + 1];
    __shared__ float Bs[BN][BK + 1];
    int b0 = blockIdx.y * BM;
    int j0 = blockIdx.x * BN;
    int tid = threadIdx.x;
    int tx = tid & 15, ty = tid >> 4;
    float acc[4][4] = {};
    int nphase = A2 ? 2 : 1;
    for (int phase = 0; phase < nphase; phase++) {
        const float* A = phase ? A2 : A1;
        const float* W = phase ? Wb : Wa;
        int ws = phase ? wb_stride : wa_stride;
        for (int k0 = 0; k0 < 128; k0 += BK) {
            __syncthreads();
            for (int i = tid; i < BM * BK; i += 256) {
                int r = i >> 5, cc = i & 31;
                int bb = b0 + r;
                As[r][cc] = (bb < B_) ? A[(size_t)bb * D + k0 + cc] : 0.f;
            }
            for (int i = tid; i < BN * BK; i += 256) {
                int r = i >> 5, cc = i & 31;
                Bs[r][cc] = W[(size_t)(j0 + r) * ws + k0 + cc];
            }
            __syncthreads();
#pragma unroll
            for (int kk = 0; kk < BK; kk++) {
                float av[4], bv[4];
#pragma unroll
                for (int i = 0; i < 4; i++) av[i] = As[ty * 4 + i][kk];
#pragma unroll
                for (int j = 0; j < 4; j++) bv[j] = Bs[tx * 4 + j][kk];
#pragma unroll
                for (int i = 0; i < 4; i++)
#pragma unroll
                    for (int j = 0; j < 4; j++) acc[i][j] += av[i] * bv[j];
            }
        }
    }
    for (int i = 0; i < 4; i++) {
        int bb = b0 + ty * 4 + i;
        if (bb >= B_) continue;
        for (int j = 0; j < 4; j++) {
            int jj = j0 + tx * 4 + j;
            gates[(size_t)bb * 512 + jj] = acc[i][j] + base[jj];
        }
    }
}

// ---------------------------------------------------------------------------
// K5: elementwise LSTM state update from gates
// ---------------------------------------------------------------------------
__global__ void lstm_elem_kernel(const float* __restrict__ gates,
                                 const float* __restrict__ c_prev, int c_bcast,
                                 float* __restrict__ c_out,
                                 float* __restrict__ h_out, int B_) {
    int t = blockIdx.x * 256 + threadIdx.x;
    if (t >= B_ * D) return;
    int b = t >> 7, d = t & (D - 1);
    const float* g = gates + (size_t)b * 512;
    float ig = 1.f / (1.f + __expf(-g[d]));
    float fg = 1.f / (1.f + __expf(-g[128 + d]));
    float gg = tanhf(g[256 + d]);
    float og = 1.f / (1.f + __expf(-g[384 + d]));
    float cp = c_bcast ? c_prev[d] : c_prev[t];
    float c = fg * cp + ig * gg;
    c_out[t] = c;
    h_out[t] = og * tanhf(c);
}

// ---------------------------------------------------------------------------
// K6: attention — REGISTER-RESIDENT tiles, no LDS at all.
// One wave per block; persistent; work-stealing via atomic counter.
// Lane (p=lane>>5, sc=lane&31) owns dim-group sc (4 dims) of rows {2j+p}.
// Tile = 16 rows = 8 float4/lane, loaded coalesced (1KB/instr, m13 pattern).
// Dot via shfl butterfly; accumulate = pure in-register FMA.
// A/B double-buffer with explicit phase unroll (static reg indexing).
// ---------------------------------------------------------------------------
__global__ __launch_bounds__(64) void attn_kernel(
    const float* __restrict__ x, const float* __restrict__ q_src, int q_bcast,
    const int* __restrict__ row_ptr, float* __restrict__ out,
    float* __restrict__ final_out, int B_, int N_, int* __restrict__ ctr) {

    const int lane = threadIdx.x;
    const int p  = lane >> 5;
    const int sc = lane & 31;
    const float4* x4 = (const float4*)x;

    auto claim = [&]() -> int {
        int v = 0;
        if (lane == 0) v = atomicAdd(ctr, 1);
        return __shfl(v, 0);
    };

    float4 xA[8], xB[8], qA, qB;
    float m, l;
    float4 acc;
    int bc, tc, ec;

    auto ISSUE = [&](float4 (&xt)[8], float4& qt, int bq, int t0, int e_) {
        const float* qp = q_bcast ? q_src : q_src + (size_t)bq * D;
        qt = ((const float4*)qp)[sc];
        int rmax = e_ - 1;
        rmax = (rmax < 0) ? 0 : rmax;
        rmax = (rmax >= N_) ? (N_ - 1) : rmax;
#pragma unroll
        for (int j = 0; j < 8; j++) {
            int rg = t0 + 2 * j + p;
            rg = (rg < rmax) ? rg : rmax;        // min; lower bound t0 >= 0
            xt[j] = x4[(size_t)rg * 32 + sc];
        }
    };

    auto COMPUTE = [&](const float4 (&xt)[8], const float4 qt, int nt) {
        float dots[8];
#pragma unroll
        for (int j = 0; j < 8; j++) {
            float4 xv = xt[j];
            float d = xv.x * qt.x + xv.y * qt.y + xv.z * qt.z + xv.w * qt.w;
            d += __shfl_xor(d, 1);
            d += __shfl_xor(d, 2);
            d += __shfl_xor(d, 4);
            d += __shfl_xor(d, 8);
            d += __shfl_xor(d, 16);              // half-wave sum: full row dot
            dots[j] = (2 * j + p < nt) ? d : -1e30f;
        }
        float mx = fmaxf(fmaxf(fmaxf(dots[0], dots[1]), fmaxf(dots[2], dots[3])),
                         fmaxf(fmaxf(dots[4], dots[5]), fmaxf(dots[6], dots[7])));
        mx = fmaxf(mx, __shfl_xor(mx, 32));      // tile max (both parities)
        if (mx > m + THR) {                      // defer-max: rare slow path
            float r = __expf(m - mx);            // first tile: exp(-inf)=0
            l *= r;
            acc.x *= r; acc.y *= r; acc.z *= r; acc.w *= r;
            m = mx;
        }
        float ts = 0.f;
#pragma unroll
        for (int j = 0; j < 8; j++) {
            float w = __expf(dots[j] - m);       // masked rows -> 0
            ts += w;
            acc.x += w * xt[j].x; acc.y += w * xt[j].y;
            acc.z += w * xt[j].z; acc.w += w * xt[j].w;
        }
        ts += __shfl_xor(ts, 32);                // add other parity's sum
        l += ts;
    };

    auto FINALIZE = [&](int bg, const float4 qt) {
        float sx = acc.x + __shfl_xor(acc.x, 32);
        float sy = acc.y + __shfl_xor(acc.y, 32);
        float sz = acc.z + __shfl_xor(acc.z, 32);
        float sw = acc.w + __shfl_xor(acc.w, 32);
        float inv = 1.f / (l + EPS);
        float4 o = {sx * inv, sy * inv, sz * inv, sw * inv};
        if (p == 0) {
            if (out) {
                ((float4*)out)[(size_t)bg * 32 + sc] = o;
            } else {
                float4* fo = (float4*)(final_out + (size_t)bg * 256);
                fo[sc] = qt;
                fo[32 + sc] = o;
            }
        }
    };

    // STEP: compute tile in (xc,qc); prefetch next tile into (xn,qn)
    auto STEP = [&](float4 (&xc)[8], float4& qc,
                    float4 (&xn)[8], float4& qn) -> bool {
        int tn = tc + ATILE;
        bool last = (tn >= ec);
        int nb = bc, ns = tn, ne = ec;
        bool have = true;
        if (last) {
            nb = claim();
            have = (nb < B_);
            if (have) { ns = row_ptr[nb]; ne = row_ptr[nb + 1]; }
        }
        if (have) ISSUE(xn, qn, nb, ns, ne);
        int nt = ec - tc;
        nt = (nt < ATILE) ? nt : ATILE;
        if (nt > 0) COMPUTE(xc, qc, nt);
        if (last) {
            FINALIZE(bc, qc);
            m = -1e30f; l = 0.f; acc = make_float4(0.f, 0.f, 0.f, 0.f);
        }
        bc = nb; tc = ns; ec = ne;
        return have;
    };

    bc = claim();
    if (bc >= B_) return;
    tc = row_ptr[bc];
    ec = row_ptr[bc + 1];
    ISSUE(xA, qA, bc, tc, ec);
    m = -1e30f; l = 0.f; acc = make_float4(0.f, 0.f, 0.f, 0.f);
    while (true) {
        if (!STEP(xA, qA, xB, qB)) break;
        if (!STEP(xB, qB, xA, qA)) break;
    }
}

// ---------------------------------------------------------------------------
extern "C" void kernel_launch(void* const* d_in, const int* in_sizes, int n_in,
                              void* d_out, int out_size, void* d_ws,
                              size_t ws_size, hipStream_t stream) {
    const float* x    = (const float*)d_in[0];
    const float* w_ih = (const float*)d_in[1];
    const float* w_hh = (const float*)d_in[2];
    const float* b_ih = (const float*)d_in[3];
    const float* b_hh = (const float*)d_in[4];
    const int*   n2g  = (const int*)d_in[5];

    int N_ = in_sizes[0] / D;     // 1,000,000
    int B_ = out_size / (2 * D);  // 10,000

    char* wsb = (char*)d_ws;
    size_t off = 0;
    auto carve = [&](size_t bytes) {
        void* pp = wsb + off;
        off = (off + bytes + 255) & ~(size_t)255;
        return pp;
    };
    int*   row_ptr = (int*)carve((size_t)(B_ + 1) * 4);
    int*   ctrs    = (int*)carve(3 * 4);
    float* b_sum   = (float*)carve(512 * 4);
    float* c1      = (float*)carve(D * 4);
    float* h1      = (float*)carve(D * 4);
    float* const2  = (float*)carve(512 * 4);
    float* W1      = (float*)carve((size_t)512 * D * 4);
    float* hbuf    = (float*)carve((size_t)B_ * D * 4);
    float* cbuf    = (float*)carve((size_t)B_ * D * 4);
    float* outbuf  = (float*)carve((size_t)B_ * D * 4);
    float* gates   = (float*)carve((size_t)B_ * 512 * 4);
    (void)ws_size;

    const float* W2 = w_ih + D;  // rows of w_ih, col offset 128, stride 256

    rowptr_kernel<<<(B_ + 1 + 255) / 256, 256, 0, stream>>>(n2g, N_, B_,
                                                            row_ptr, ctrs);
    init_consts_kernel<<<1, 512, 0, stream>>>(b_ih, b_hh, b_sum, c1, h1);
    init_w1_kernel<<<512, 128, 0, stream>>>(w_ih, w_hh, b_sum, h1, W1, const2);

    dim3 ggrid(512 / BN, (B_ + BM - 1) / BM);
    int  egrid = (B_ * D + 255) / 256;

    // step 1: query = h1 (broadcast) -> out1
    attn_kernel<<<AGRID, 64, 0, stream>>>(x, h1, 1, row_ptr, outbuf, nullptr,
                                          B_, N_, ctrs + 0);
    // step 2: gates = const2 + out1 @ W2^T ; c_prev = c1 (broadcast)
    lstm_gemm_kernel<<<ggrid, 256, 0, stream>>>(outbuf, W2, 256, nullptr,
                                                nullptr, 0, const2, gates, B_);
    lstm_elem_kernel<<<egrid, 256, 0, stream>>>(gates, c1, 1, cbuf, hbuf, B_);
    attn_kernel<<<AGRID, 64, 0, stream>>>(x, hbuf, 0, row_ptr, outbuf, nullptr,
                                          B_, N_, ctrs + 1);
    // step 3: gates = b_sum + h2 @ W1^T + out2 @ W2^T
    lstm_gemm_kernel<<<ggrid, 256, 0, stream>>>(hbuf, W1, 128, outbuf, W2, 256,
                                                b_sum, gates, B_);
    lstm_elem_kernel<<<egrid, 256, 0, stream>>>(gates, cbuf, 0, cbuf, hbuf, B_);
    // step 3 attention writes final q_star = [h3, out3] directly to d_out
    attn_kernel<<<AGRID, 64, 0, stream>>>(x, hbuf, 0, row_ptr, nullptr,
                                          (float*)d_out, B_, N_, ctrs + 2);
}